// Round 9
// baseline (102.483 us; speedup 1.0000x reference)
//
#include <hip/hip_runtime.h>
#include <hip/hip_fp16.h>

#define G 8192
#define IMG_W 512
#define IMG_H 512
#define TILE 16
#define NTX (IMG_W / TILE)   // 32 x-tiles (16 px)
#define NTY8 (IMG_H / 8)     // 64 y-strips (8 px)
#define BLK 256
#define CAP 1024             // per-half-tile list capacity (avg ~139)
#define ALPHA_THRESH (1.0f/255.0f)
#define ALPHA_CAP 0.99f
#define TRANS_THRESH 1e-4f

// -----------------------------------------------------------------------
// Kernel 0: per-gaussian span, x in 16-px tiles [0,32), y in 8-px strips
// [0,64), packed u8x4 into one u32. Exact cull (validated): alpha>=1/255
// requires sigma <= smax = ln(255*op); ellipse AABB half-extents
// sqrt(2*smax*(A^-1)_ii), inflated so rounding can't exclude falsely.
// x-tile t covers centers [16t+0.5,16t+15.5]; y-strip t covers
// [8t+0.5, 8t+7.5] -> tymin8=ceil((ymin-7.5)/8), tymax8=floor((ymax-.5)/8).
// -----------------------------------------------------------------------
__global__ __launch_bounds__(BLK)
void range_kernel(const float* __restrict__ means2d,
                  const float* __restrict__ conics,
                  const float* __restrict__ opac,
                  unsigned int* __restrict__ ranges)
{
    int g = blockIdx.x * BLK + threadIdx.x;
    if (g >= G) return;
    float op = opac[g];
    unsigned int packed = 0xFFu;          // culled: txmin=255 matches nothing
    if (op * 255.0f >= 1.0f) {
        float smax = __logf(op * 255.0f);
        float a = conics[3*g], b = conics[3*g+1], c = conics[3*g+2];
        float det = fmaxf(a * c - b * b, 1e-12f);
        float rx = sqrtf(fmaxf(2.0f * smax * c / det, 0.0f)) * 1.0001f + 0.01f;
        float ry = sqrtf(fmaxf(2.0f * smax * a / det, 0.0f)) * 1.0001f + 0.01f;
        float mx = means2d[2*g], my = means2d[2*g+1];
        int txmin = (int)ceilf ((mx - rx - 15.5f) * 0.0625f);
        int txmax = (int)floorf((mx + rx -  0.5f) * 0.0625f);
        int tymin = (int)ceilf ((my - ry -  7.5f) * 0.125f);
        int tymax = (int)floorf((my + ry -  0.5f) * 0.125f);
        if (!(txmax < 0 || txmin > NTX-1 || tymax < 0 || tymin > NTY8-1 ||
              txmin > txmax || tymin > tymax)) {
            txmin = max(txmin, 0); txmax = min(txmax, NTX-1);
            tymin = max(tymin, 0); tymax = min(tymax, NTY8-1);
            packed = (unsigned)txmin | ((unsigned)txmax << 8)
                   | ((unsigned)tymin << 16) | ((unsigned)tymax << 24);
        }
    }
    ranges[g] = packed;
}

__device__ __forceinline__ int hitp(unsigned p, unsigned btx, unsigned bty)
{
    return (btx >= (p & 0xffu)) & (btx <= ((p >> 8) & 0xffu)) &
           (bty >= ((p >> 16) & 0xffu)) & (bty <= (p >> 24));
}

// -----------------------------------------------------------------------
// Fused half-tile kernel: ONE WAVE (64 thr) per 16x8 half-tile, 2048
// blocks (8/CU — fine-grained for load balance). Single wave => all
// __syncthreads() compile to waitcnt-only (no s_barrier), votes are
// wave-uniform.
//  Phase 1: ONE-pass scan of the 32 KB range table (uint4 loads), ballot
//           compaction with running in-wave prefix; writes (depth,idx)
//           keys directly (index-ordered).
//  Phase 2: validated rank sort by (depth_bits<<13)|idx — stable argsort
//           restricted to this half-tile.
//  Phase 3: validated R8 compositing: chunks of 64 records staged to LDS
//           as 2 x float4 ({mx,my,a/2,b},{c/2,op,rg(half2),blue}); 2
//           px/lane sharing x; wave vote every 8 records (err <= 1e-4).
// -----------------------------------------------------------------------
__global__ __launch_bounds__(64)
void tile_kernel(const unsigned int* __restrict__ ranges,
                 const float* __restrict__ depths,
                 const float* __restrict__ means2d,
                 const float* __restrict__ conics,
                 const float* __restrict__ colors,
                 const float* __restrict__ opac,
                 float*       __restrict__ out)
{
    __shared__ unsigned long long keys[CAP];   // 8 KB
    __shared__ unsigned short slist[CAP];      // 2 KB
    __shared__ float4 buf[128];                // 2 KB

    const int lane = threadIdx.x;
    const unsigned btx = blockIdx.x, bty = blockIdx.y;

    // ---- Phase 1: one-pass ballot compaction (single wave) ----
    const uint4* r4 = (const uint4*)ranges;
    const unsigned long long lt = (1ull << lane) - 1ull;
    int pos = 0;                               // wave-uniform running count
    for (int i = 0; i < 32; ++i) {             // 32 x 256 gaussians
        uint4 rv = r4[i * 64 + lane];
        int gbase = i * 256 + lane * 4;
        int h0 = hitp(rv.x, btx, bty), h1 = hitp(rv.y, btx, bty);
        int h2 = hitp(rv.z, btx, bty), h3 = hitp(rv.w, btx, bty);
        unsigned long long m0 = __ballot(h0), m1 = __ballot(h1);
        unsigned long long m2 = __ballot(h2), m3 = __ballot(h3);
        int p = pos + __popcll(m0 & lt) + __popcll(m1 & lt)
                    + __popcll(m2 & lt) + __popcll(m3 & lt);
        if (h0 && p < CAP) {
            keys[p] = ((unsigned long long)__float_as_uint(depths[gbase]) << 13)
                    | (unsigned)gbase;
        }
        p += h0;
        if (h1 && p < CAP) {
            keys[p] = ((unsigned long long)__float_as_uint(depths[gbase+1]) << 13)
                    | (unsigned)(gbase + 1);
        }
        p += h1;
        if (h2 && p < CAP) {
            keys[p] = ((unsigned long long)__float_as_uint(depths[gbase+2]) << 13)
                    | (unsigned)(gbase + 2);
        }
        p += h2;
        if (h3 && p < CAP) {
            keys[p] = ((unsigned long long)__float_as_uint(depths[gbase+3]) << 13)
                    | (unsigned)(gbase + 3);
        }
        pos += __popcll(m0) + __popcll(m1) + __popcll(m2) + __popcll(m3);
    }
    const int N = min(pos, CAP);
    __syncthreads();    // single wave: waitcnt only

    // ---- Phase 2: rank sort (stable argsort by (depth, idx)) ----
    for (int i = lane; i < N; i += 64) {
        unsigned long long ke = keys[i];
        int r = 0;
        #pragma unroll 4
        for (int j = 0; j < N; ++j) r += (keys[j] < ke);
        slist[r] = (unsigned short)(ke & 0x1fffull);
    }
    __syncthreads();

    // ---- Phase 3: 2 px/lane compositing over 16x8 half-tile ----
    const int x  = btx * TILE + (lane & 15);
    const int y0 = bty * 8 + (lane >> 4);      // rows 0..3 of the strip
    const float px  = (float)x  + 0.5f;
    const float py0 = (float)y0 + 0.5f;
    const float py1 = py0 + 4.0f;              // rows 4..7

    float T0 = 1.f, T1 = 1.f;
    float r0a = 0.f, g0a = 0.f, b0a = 0.f;
    float r1a = 0.f, g1a = 0.f, b1a = 0.f;
    bool done = false;

    for (int base = 0; base < N && !done; base += 64) {
        const int n = min(64, N - base);
        float4 q0 = make_float4(0.f, 0.f, 0.f, 0.f);   // padded: exact no-op
        float4 q1 = make_float4(0.f, 0.f, 0.f, 0.f);
        if (lane < n) {
            int idx = slist[base + lane];
            union { float f; __half2 h; } uc;
            uc.h = __floats2half2_rn(colors[3*idx], colors[3*idx + 1]);
            q0 = make_float4(means2d[2*idx], means2d[2*idx + 1],
                             0.5f * conics[3*idx], conics[3*idx + 1]);
            q1 = make_float4(0.5f * conics[3*idx + 2], opac[idx],
                             uc.f, colors[3*idx + 2]);
        }
        buf[lane * 2] = q0; buf[lane * 2 + 1] = q1;
        __syncthreads();    // waitcnt only

        const int n8 = (n + 7) & ~7;
        for (int j = 0; j < n8 && !done; j += 8) {
            #pragma unroll
            for (int u = 0; u < 8; ++u) {
                float4 c0 = buf[(j + u) * 2];        // ds_read_b128 bcast
                float4 c1 = buf[(j + u) * 2 + 1];
                float dx  = px - c0.x;
                float bdx = c0.w * dx;
                float txx = c0.z * dx * dx;
                float dy0 = py0 - c0.y;
                float dy1 = py1 - c0.y;
                float s0  = fmaf(fmaf(c1.x, dy0, bdx), dy0, txx);
                float s1  = fmaf(fmaf(c1.x, dy1, bdx), dy1, txx);
                union { float f; __half2 h; } uc; uc.f = c1.z;
                float cr = __low2float(uc.h);
                float cg = __high2float(uc.h);
                float cb = c1.w;
                float e0 = c1.y * __expf(-s0);
                float e1 = c1.y * __expf(-s1);
                float a0 = (s0 >= 0.f && e0 >= ALPHA_THRESH)
                         ? fminf(e0, ALPHA_CAP) : 0.f;
                float a1 = (s1 >= 0.f && e1 >= ALPHA_THRESH)
                         ? fminf(e1, ALPHA_CAP) : 0.f;
                float w0 = a0 * T0, w1 = a1 * T1;
                r0a = fmaf(w0, cr, r0a); g0a = fmaf(w0, cg, g0a);
                b0a = fmaf(w0, cb, b0a);
                r1a = fmaf(w1, cr, r1a); g1a = fmaf(w1, cg, g1a);
                b1a = fmaf(w1, cb, b1a);
                T0 *= (1.f - a0); T1 *= (1.f - a1);
            }
            // wave-uniform exit (single wave = whole block)
            if (!__any(fmaxf(T0, T1) >= TRANS_THRESH)) done = true;
        }
        __syncthreads();    // order buf reuse vs reads (waitcnt only)
    }

    int o = (y0 * IMG_W + x) * 3;
    out[o] = r0a; out[o + 1] = g0a; out[o + 2] = b0a;   // BG = 0
    o = ((y0 + 4) * IMG_W + x) * 3;
    out[o] = r1a; out[o + 1] = g1a; out[o + 2] = b1a;
}

extern "C" void kernel_launch(void* const* d_in, const int* in_sizes, int n_in,
                              void* d_out, int out_size, void* d_ws, size_t ws_size,
                              hipStream_t stream)
{
    const float* means2d = (const float*)d_in[0];  // (G,2)
    const float* conics  = (const float*)d_in[1];  // (G,3)
    const float* colors  = (const float*)d_in[2];  // (G,3)
    const float* opac    = (const float*)d_in[3];  // (G,)
    const float* depths  = (const float*)d_in[4];  // (G,)
    float* out = (float*)d_out;
    unsigned int* ranges = (unsigned int*)d_ws;    // G u32 = 32 KB of ws

    range_kernel<<<G / BLK, BLK, 0, stream>>>(means2d, conics, opac, ranges);
    tile_kernel<<<dim3(NTX, NTY8), 64, 0, stream>>>(
        ranges, depths, means2d, conics, colors, opac, out);
}